// Round 1
// baseline (413.252 us; speedup 1.0000x reference)
//
#include <hip/hip_runtime.h>

// S_GC_att_A: fused 1x1-conv (256->7*256 ch) + per-partition adjacency contraction.
// z-first factorization: z[ci,tw] = sum_v x[ci,t,v]*M_k[v,w]  (MFMA, K padded 22->32)
//                        out[c,tw] += sum_ci W_k[c,ci]*z[ci,tw] (MFMA, K=256 in 2 chunks)
// bias: out += sum_k b[k*256+c] * S_k[w],  S_k[w] = sum_v M_k[v,w]  (epilogue)
//
// Block = (t-tile of 4, n). 256 threads (4 waves). All 256 output channels per block.
// LDS 63,136 B (<64 KB) -> 2 blocks/CU resident.

#define TT   4
#define NTW  88     // TT*22
#define XSTR 104    // x LDS row stride: 4*24 + 8 pad (stride 208 B -> 2-way banks)
#define MROWS 176   // 7*24 + 8 tail pad

typedef __attribute__((ext_vector_type(8))) __bf16 bf16x8;
typedef __attribute__((ext_vector_type(4))) float  f32x4;
typedef __attribute__((ext_vector_type(8))) short  s16x8;
typedef __attribute__((ext_vector_type(4))) short  s16x4;

__device__ __forceinline__ unsigned short f2bf(float f) {   // RNE f32 -> bf16 bits
  union { float f; unsigned u; } x; x.f = f;
  return (unsigned short)((x.u + 0x7FFFu + ((x.u >> 16) & 1u)) >> 16);
}

__device__ __forceinline__ bf16x8 cvt8(float4 a, float4 b) {
  s16x8 r;
  r[0] = (short)f2bf(a.x); r[1] = (short)f2bf(a.y);
  r[2] = (short)f2bf(a.z); r[3] = (short)f2bf(a.w);
  r[4] = (short)f2bf(b.x); r[5] = (short)f2bf(b.y);
  r[6] = (short)f2bf(b.z); r[7] = (short)f2bf(b.w);
  return __builtin_bit_cast(bf16x8, r);
}

__global__ __launch_bounds__(256, 2)
void sgc_fused(const float* __restrict__ x, const float* __restrict__ Ag,
               const float* __restrict__ attA, const float* __restrict__ W,
               const float* __restrict__ b, float* __restrict__ out) {
  const int tt   = blockIdx.x;        // 0..127  (t-tile of 4)
  const int n    = blockIdx.y;        // 0..7
  const int tid  = threadIdx.x;
  const int wave = tid >> 6;
  const int lane = tid & 63;
  const int l15  = lane & 15;
  const int l4   = lane >> 4;

  // LDS carve: Xs [128][104] bf16 (26,624) | Zs [96][128] bf16 swizzled (24,576)
  //            Ms [176][32] bf16 (11,264)  | Ss [7][24] f32 (672)  = 63,136 B
  __shared__ __align__(16) char smem[63136];
  unsigned short* Xs = (unsigned short*)(smem);
  unsigned short* Zs = (unsigned short*)(smem + 26624);
  unsigned short* Ms = (unsigned short*)(smem + 51200);
  float*          Ss = (float*)(smem + 62464);
  float*          B2 = (float*)(smem);          // reuses Xs space after k-loop: [256][25] f32

  // main-GEMM accumulators: 16 Mtiles (c) x 6 Ntiles (tw) split 4 Mtiles/wave
  f32x4 acc[4][6];
  #pragma unroll
  for (int i = 0; i < 4; ++i)
    #pragma unroll
    for (int j = 0; j < 6; ++j)
      acc[i][j] = (f32x4){0.f, 0.f, 0.f, 0.f};

  // ---- block init: M~[k][w][v] = M_k[v][w] (bf16, zero-padded v>=22 / tail rows) ----
  for (int i = tid; i < MROWS * 32; i += 256) {
    int row = i >> 5, v = i & 31;
    int k = row / 24, w = row - k * 24;
    float val = 0.f;
    if (row < 168 && w < 22 && v < 22)
      val = (k < 3) ? Ag[(k * 22 + v) * 22 + w]
                    : attA[(((n << 2) + (k - 3)) * 22 + v) * 22 + w];
    Ms[i] = f2bf(val);
  }
  // S[k][w] = sum_v M_k[v][w]  (fp32, exact)
  if (tid < 168) {
    int k = tid / 24, w = tid - k * 24;
    float s = 0.f;
    if (w < 22) {
      for (int v = 0; v < 22; ++v)
        s += (k < 3) ? Ag[(k * 22 + v) * 22 + w]
                     : attA[(((n << 2) + (k - 3)) * 22 + v) * 22 + w];
    }
    Ss[tid] = s;
  }
  // zero Zs pad rows 88..95 (read by Ntile 5, results discarded but must be finite)
  for (int i = tid; i < 1024; i += 256) Zs[88 * 128 + i] = 0;
  // zero ALL of Xs: pad slots feed MFMA A-frags; garbage NaN * 0 = NaN would poison z
  for (int i = tid; i < 128 * XSTR / 2; i += 256) ((unsigned*)Xs)[i] = 0;
  __syncthreads();

  for (int chunk = 0; chunk < 2; ++chunk) {
    // ---- stage x[n, chunk*128..+128, tt*4..+4, :] -> Xs bf16 [ci][t][24v] ----
    // global float4 fully coalesced (tv contiguous); 4x b16 LDS writes handle the
    // 22->24 v-pad remap (no transpose needed: z-GEMM A-frags want v-contiguous).
    for (int i = tid; i < 128 * 22; i += 256) {
      int ci = i / 22, q = i - ci * 22;
      const float4 f4 = *(const float4*)(x + (size_t)((n * 256 + chunk * 128 + ci) * 11264)
                                           + tt * NTW + q * 4);
      float vv[4] = {f4.x, f4.y, f4.z, f4.w};
      int tv0 = q * 4;
      #pragma unroll
      for (int j = 0; j < 4; ++j) {
        int tv = tv0 + j;
        int t = tv / 22, v = tv - t * 22;
        Xs[ci * XSTR + t * 24 + v] = f2bf(vv[j]);
      }
    }
    __syncthreads();

    for (int k = 0; k < 7; ++k) {
      // ---- z phase: z_t[ci,w] = X_t[ci,v] @ M_k[v,w], one K=32 MFMA step ----
      bf16x8 bm0 = *(const bf16x8*)(&Ms[(k * 24 + l15) * 32 + l4 * 8]);
      bf16x8 bm1 = *(const bf16x8*)(&Ms[(k * 24 + 16 + l15) * 32 + l4 * 8]);
      f32x4 zt[2][4][2];
      #pragma unroll
      for (int mi = 0; mi < 2; ++mi) {
        int mt = wave * 2 + mi;                       // local ci Mtile (0..7)
        #pragma unroll
        for (int t = 0; t < 4; ++t) {
          bf16x8 ax = *(const bf16x8*)(&Xs[(mt * 16 + l15) * XSTR + t * 24 + l4 * 8]);
          zt[mi][t][0] = __builtin_amdgcn_mfma_f32_16x16x32_bf16(ax, bm0, (f32x4){0.f,0.f,0.f,0.f}, 0, 0, 0);
          zt[mi][t][1] = __builtin_amdgcn_mfma_f32_16x16x32_bf16(ax, bm1, (f32x4){0.f,0.f,0.f,0.f}, 0, 0, 0);
        }
      }
      // write z (C-layout regs) -> Zs[tw][ci] with XOR-swizzled 8-elem blocks (2-way banks)
      #pragma unroll
      for (int mi = 0; mi < 2; ++mi) {
        int ci0 = (wave * 2 + mi) * 16 + l4 * 4;      // 4 consecutive ci rows per lane
        int cb = ci0 >> 3, sub = ci0 & 7;
        #pragma unroll
        for (int ni = 0; ni < 2; ++ni) {
          int w = ni * 16 + l15;
          if (w < 22) {
            #pragma unroll
            for (int t = 0; t < 4; ++t) {
              int tw = t * 22 + w;
              int eo = tw * 128 + ((cb ^ (tw & 15)) << 3) + sub;
              f32x4 z = zt[mi][t][ni];
              s16x4 pk;
              pk[0] = (short)f2bf(z[0]); pk[1] = (short)f2bf(z[1]);
              pk[2] = (short)f2bf(z[2]); pk[3] = (short)f2bf(z[3]);
              *(s16x4*)(&Zs[eo]) = pk;                // 8 B write, 8 B aligned
            }
          }
        }
      }
      __syncthreads();

      // ---- main GEMM partial-K: out[c,tw] += W_k[c, ci-chunk] @ z ----
      #pragma unroll
      for (int s = 0; s < 4; ++s) {
        bf16x8 wf[4];
        #pragma unroll
        for (int mi = 0; mi < 4; ++mi) {
          int c = (wave * 4 + mi) * 16 + l15;
          const float* wp = W + (size_t)((k * 256 + c) * 256) + chunk * 128 + s * 32 + l4 * 8;
          wf[mi] = cvt8(*(const float4*)wp, *(const float4*)(wp + 4));  // A-frag from global fp32
        }
        int cb = (s << 2) + l4;
        #pragma unroll
        for (int ni = 0; ni < 6; ++ni) {
          int tw = ni * 16 + l15;
          bf16x8 zf = *(const bf16x8*)(&Zs[tw * 128 + ((cb ^ (tw & 15)) << 3)]);
          #pragma unroll
          for (int mi = 0; mi < 4; ++mi)
            acc[mi][ni] = __builtin_amdgcn_mfma_f32_16x16x32_bf16(wf[mi], zf, acc[mi][ni], 0, 0, 0);
        }
      }
      __syncthreads();   // before next k overwrites Zs / next chunk overwrites Xs
    }
  }

  // ---- bias2[c][w] = sum_k b[k*256+c] * S_k[w]  (Xs space is dead -> reuse) ----
  for (int i = tid; i < 256 * 22; i += 256) {
    int c = i / 22, w = i - c * 22;
    float s = 0.f;
    #pragma unroll
    for (int k = 0; k < 7; ++k) s += b[k * 256 + c] * Ss[k * 24 + w];
    B2[c * 25 + w] = s;
  }
  __syncthreads();

  // ---- epilogue: bias add + store (C-layout: col=tw=lane&15+16*ni, rows=l4*4+r) ----
  int tg0 = tt * TT;
  #pragma unroll
  for (int ni = 0; ni < 6; ++ni) {
    int tw = ni * 16 + l15;
    if (tw < NTW) {
      int t = tw / 22, w = tw - t * 22;
      #pragma unroll
      for (int mi = 0; mi < 4; ++mi) {
        int c0 = (wave * 4 + mi) * 16 + l4 * 4;
        #pragma unroll
        for (int r = 0; r < 4; ++r) {
          int c = c0 + r;
          out[(size_t)((n * 256 + c) * 512 + tg0 + t) * 22 + w] = acc[mi][ni][r] + B2[c * 25 + w];
        }
      }
    }
  }
}

extern "C" void kernel_launch(void* const* d_in, const int* in_sizes, int n_in,
                              void* d_out, int out_size, void* d_ws, size_t ws_size,
                              hipStream_t stream) {
  (void)in_sizes; (void)n_in; (void)d_ws; (void)ws_size; (void)out_size;
  const float* x    = (const float*)d_in[0];
  const float* Ag   = (const float*)d_in[1];
  const float* attA = (const float*)d_in[2];
  const float* W    = (const float*)d_in[3];
  const float* b    = (const float*)d_in[4];
  float* out = (float*)d_out;
  dim3 grid(128, 8, 1);     // (t-tiles, n)
  sgc_fused<<<grid, 256, 0, stream>>>(x, Ag, attA, W, b, out);
}